// Round 7
// baseline (70.402 us; speedup 1.0000x reference)
//
#include <hip/hip_runtime.h>

#define NSCALES 20
#define PATCH 100
#define IMGS_PER_SCALE 1600
#define TOTAL_IMGS 32000
#define THREADS 256
#define PXT 8                           // pixels per thread
#define CHUNKPX (THREADS * PXT)         // 2048 pixels per block
#define S2MAX 1681

struct Ptrs   { const float* p[NSCALES]; };
struct Starts { int chunkStart[NSCALES]; };

// ---------------------------------------------------------------------------
// Kernel 1 (templated on S): background-pixel detector.
// Thread t tests pixels P0 + t + i*256 (lane-contiguous 12B loads, i=0..7).
// Common case: no background pixel in the wave -> no LDS, no barrier, no
// store, no atomic. Rare bg pixel -> one global atomicAdd (order-independent
// => deterministic). Per-image count reconstructed later as s^2 - bg.
// ---------------------------------------------------------------------------
template<int S>
__device__ __forceinline__ void count_chunk(const float* __restrict__ x,
                                            int chunkLocal, int sc,
                                            int* __restrict__ bgCnt)
{
    constexpr int S2 = S * S;
    constexpr int ROWDIV = 100 * S;               // j = P / (100*S)
    const int Ntot = IMGS_PER_SCALE * S2;
    const int P0   = chunkLocal * CHUNKPX + (int)threadIdx.x;

    float p0[PXT], p1[PXT], p2[PXT];
    float c0[PXT], c1[PXT], c2[PXT];
    #pragma unroll
    for (int i = 0; i < PXT; i++) {
        const int Pc = min(P0 + i * THREADS, Ntot - 1);
        const float* p = x + (size_t)Pc * 3;      // 12B lane-contiguous
        p0[i] = p[0]; p1[i] = p[1]; p2[i] = p[2];
        const int j = Pc / ROWDIV;                // constant-divisor magic
        const float* c = x + (size_t)(((j * PATCH + 49) * S + (S >> 1)) * 3);
        c0[i] = c[0]; c1[i] = c[1]; c2[i] = c[2]; // broadcast (L1-coalesced)
    }
    unsigned bgm = 0;
    #pragma unroll
    for (int i = 0; i < PXT; i++) {
        float d = fmaxf(fmaxf(fabsf(p0[i] - c0[i]), fabsf(p1[i] - c1[i])),
                        fabsf(p2[i] - c2[i]));
        if (d > (float)S && (P0 + i * THREADS) < Ntot) bgm |= 1u << i;
    }
    if (bgm) {                                    // rare: execz-skipped
        #pragma unroll
        for (int i = 0; i < PXT; i++) {
            if (bgm & (1u << i)) {
                int img = (P0 + i * THREADS) / S2;
                atomicAdd(&bgCnt[sc * IMGS_PER_SCALE + img], 1);
            }
        }
    }
}

__global__ __launch_bounds__(THREADS)
void count_kernel(Ptrs ptrs, Starts st, int* __restrict__ bgCnt)
{
    const int bid = blockIdx.x;
    int sc = 0;
    #pragma unroll
    for (int k = 1; k < NSCALES; k++) sc += (bid >= st.chunkStart[k]) ? 1 : 0;
    const int cl = bid - st.chunkStart[sc];

    switch (sc) {
#define CASE(i) case i: count_chunk<3 + 2*(i)>(ptrs.p[i], cl, i, bgCnt); break;
        CASE(0)  CASE(1)  CASE(2)  CASE(3)  CASE(4)
        CASE(5)  CASE(6)  CASE(7)  CASE(8)  CASE(9)
        CASE(10) CASE(11) CASE(12) CASE(13) CASE(14)
        CASE(15) CASE(16) CASE(17) CASE(18) CASE(19)
#undef CASE
    }
}

// ---------------------------------------------------------------------------
// Kernel 2: classify + CC for partial images. 500 blocks x 64 images.
// cnt = s^2 - bg. Analytic fast paths; wave-shuffle CC for s<=7; block LDS
// CC for s>=9 (vanishingly rare).
// ---------------------------------------------------------------------------
__global__ __launch_bounds__(THREADS)
void cc_kernel(Ptrs ptrs, const int* __restrict__ bgCnt,
               int* __restrict__ wsCnt,
               int* __restrict__ wsNcomp, int* __restrict__ wsMaxc)
{
    const int bid = blockIdx.x;                 // 25 blocks per scale
    const int sc  = bid / 25;
    const int s   = 3 + 2 * sc;
    const int s2  = s * s;
    const int BIGL = s2 + 1;
    const float* __restrict__ x = ptrs.p[sc];
    const int imgLoc0 = (bid % 25) * 64;
    const int tid = threadIdx.x;
    const unsigned mS = 0xFFFFFFFFu / (unsigned)s + 1;

    __shared__ int slowList[64];
    __shared__ int nslow;
    __shared__ int lab[S2MAX];
    __shared__ int szh[S2MAX];
    __shared__ int redN[4], redM[4];

    if (tid == 0) nslow = 0;
    __syncthreads();
    if (tid < 64) {
        int img = imgLoc0 + tid;
        int g = sc * IMGS_PER_SCALE + img;
        int c = s2 - bgCnt[g];
        wsCnt[g] = c;
        if (c == s2)      { wsNcomp[g] = 1; wsMaxc[g] = s2; }
        else if (c == 0)  { wsNcomp[g] = 0; wsMaxc[g] = 0; }
        else { int k = atomicAdd(&nslow, 1); slowList[k] = img; }
    }
    __syncthreads();
    const int ns = nslow;
    if (ns == 0) return;

    if (s2 <= 64) {
        // ---- per-wave shuffle CC, one image per wave iteration ----
        const int w = tid >> 6, l = tid & 63;
        for (int idx = w; idx < ns; idx += 4) {
            int img = slowList[idx];
            int fg = 0, labr = BIGL, i1 = 0, i2 = 0;
            if (l < s2) {
                i1 = (int)__umulhi((unsigned)l, mS);
                i2 = l - i1 * s;
                int M = img * s + i1;
                int j = M / PATCH;
                const float* ce = x + (size_t)(((j * PATCH + 49) * s + (s >> 1)) * 3);
                const float* px = x + ((size_t)img * s2 + l) * 3;
                float d = fmaxf(fmaxf(fabsf(px[0] - ce[0]), fabsf(px[1] - ce[1])),
                                fabsf(px[2] - ce[2]));
                if (d <= (float)s) { fg = 1; labr = l + 1; }
            }
            for (;;) {
                int m = labr;
                int vU = __shfl(labr, (l - s) & 63);
                int vD = __shfl(labr, (l + s) & 63);
                int vL = __shfl(labr, (l - 1) & 63);
                int vR = __shfl(labr, (l + 1) & 63);
                if (fg) {
                    if (i1 > 0)     m = min(m, vU);
                    if (i1 < s - 1) m = min(m, vD);
                    if (i2 > 0)     m = min(m, vL);
                    if (i2 < s - 1) m = min(m, vR);
                }
                int vJ = __shfl(labr, (m - 1) & 63);      // pointer jump
                if (fg) m = min(m, vJ);
                unsigned long long chg = __ballot(m < labr);
                labr = m;
                if (chg == 0) break;
            }
            int ncomp = __popcll(__ballot(fg && labr == l + 1));
            int mc = 0;
            for (int r = 0; r < s2; r++) {
                int szr = __popcll(__ballot(fg && labr == r + 1));
                mc = max(mc, szr);
            }
            if (l == 0) {
                int g = sc * IMGS_PER_SCALE + img;
                wsNcomp[g] = ncomp; wsMaxc[g] = mc;
            }
        }
    } else {
        // ---- block-sequential LDS CC (bg pixel at s>=9: vanishingly rare) --
        for (int idx = 0; idx < ns; idx++) {
            int img = slowList[idx];
            const int ibase = img * s2 * 3;
            for (int i = tid; i < s2; i += THREADS) {
                int i1 = (int)__umulhi((unsigned)i, mS);
                int M = img * s + i1;
                int j = M / PATCH;
                const float* ce = x + (size_t)(((j * PATCH + 49) * s + (s >> 1)) * 3);
                const float* px = x + ibase + i * 3;
                float d = fmaxf(fmaxf(fabsf(px[0] - ce[0]), fabsf(px[1] - ce[1])),
                                fabsf(px[2] - ce[2]));
                lab[i] = (d <= (float)s) ? (i + 1) : BIGL;
                szh[i] = 0;
            }
            __syncthreads();
            for (;;) {
                bool changed = false;
                for (int i = tid; i < s2; i += THREADS) {
                    int L0 = lab[i];
                    if (L0 <= s2) {
                        int i1 = (int)__umulhi((unsigned)i, mS);
                        int i2 = i - i1 * s;
                        int m = L0;
                        if (i1 > 0)     m = min(m, lab[i - s]);
                        if (i1 < s - 1) m = min(m, lab[i + s]);
                        if (i2 > 0)     m = min(m, lab[i - 1]);
                        if (i2 < s - 1) m = min(m, lab[i + 1]);
                        m = min(m, lab[m - 1]);
                        if (m < L0) { lab[i] = m; changed = true; }
                    }
                }
                if (__syncthreads_count(changed ? 1 : 0) == 0) break;
            }
            int ncomp = 0;
            for (int i = tid; i < s2; i += THREADS) {
                int L = lab[i];
                if (L <= s2) {
                    atomicAdd(&szh[L - 1], 1);
                    if (L == i + 1) ncomp++;
                }
            }
            __syncthreads();
            int mc = 0;
            for (int i = tid; i < s2; i += THREADS) mc = max(mc, szh[i]);
            for (int m = 32; m >= 1; m >>= 1) {
                ncomp += __shfl_xor(ncomp, m);
                mc     = max(mc, __shfl_xor(mc, m));
            }
            int wid = tid >> 6, lane = tid & 63;
            if (lane == 0) { redN[wid] = ncomp; redM[wid] = mc; }
            __syncthreads();
            if (tid == 0) {
                int g = sc * IMGS_PER_SCALE + img;
                wsNcomp[g] = redN[0] + redN[1] + redN[2] + redN[3];
                wsMaxc[g]  = max(max(redM[0], redM[1]), max(redM[2], redM[3]));
            }
            __syncthreads();
        }
    }
}

// ---------------------------------------------------------------------------
// Kernel 3: per-scale finalization (verified).
// ---------------------------------------------------------------------------
__global__ __launch_bounds__(THREADS)
void final_kernel(const int* __restrict__ wsCnt,
                  const int* __restrict__ wsNcomp,
                  const int* __restrict__ wsMaxc,
                  float* __restrict__ out)
{
    const int scale = blockIdx.x;
    const int s  = 3 + 2 * scale;
    const int s2 = s * s;
    const int tid = threadIdx.x;
    const int NB = IMGS_PER_SCALE;
    const int CH = 7;

    __shared__ int nc[IMGS_PER_SCALE];
    __shared__ int tsum[THREADS];

    for (int i = tid; i < NB; i += THREADS) nc[i] = wsNcomp[scale * NB + i];
    __syncthreads();

    int lsum = 0;
    for (int k = 0; k < CH; k++) {
        int idx = tid * CH + k;
        if (idx < NB) lsum += nc[idx];
    }
    tsum[tid] = lsum;
    __syncthreads();
    for (int st = 1; st < THREADS; st <<= 1) {
        int v = (tid >= st) ? tsum[tid - st] : 0;
        __syncthreads();
        tsum[tid] += v;
        __syncthreads();
    }
    int run = (tid > 0) ? tsum[tid - 1] : 0;
    for (int k = 0; k < CH; k++) {
        int idx = tid * CH + k;
        if (idx < NB) {
            int v = nc[idx];
            run += v;
            nc[idx] = (v > 0) ? run : 0;
        }
    }
    __syncthreads();

    int b    = tid >> 4;
    int lane = tid & 15;
    float fdsum = 0.f, sn = 0.f, sn2 = 0.f, pcsum = 0.f;
    int pqc = 0, bg = 0, mcx = 0;
    for (int q = lane; q < PATCH; q += 16) {
        int i = b * PATCH + q;
        int c = wsCnt[scale * NB + i];
        float n = (c > 0) ? (float)c : 1.0f;
        fdsum += 1.0f / n;
        sn    += n;
        sn2   += n * n;
        pqc   += ((float)c / (float)s2 >= 0.59275f) ? 1 : 0;
        bg    += (s2 - c);
        mcx    = max(mcx, wsMaxc[scale * NB + i]);
        pcsum += (float)nc[i];
    }
    for (int m = 8; m >= 1; m >>= 1) {
        fdsum += __shfl_xor(fdsum, m);
        sn    += __shfl_xor(sn, m);
        sn2   += __shfl_xor(sn2, m);
        pcsum += __shfl_xor(pcsum, m);
        pqc   += __shfl_xor(pqc, m);
        bg    += __shfl_xor(bg, m);
        mcx    = max(mcx, __shfl_xor(mcx, m));
    }
    if (lane == 0) {
        float fd  = fdsum / 100.0f;
        float m1  = sn / 100.0f;
        float mu1 = m1 * m1;
        float mu2 = sn2 / 100.0f;
        float lac = (mu2 - mu1) / mu1;
        float pq  = (float)pqc / 100.0f;
        float pc  = pcsum / 100.0f;
        float pm  = (float)max(bg, mcx);
        out[b * 100 +  0 + scale] = pc;
        out[b * 100 + 20 + scale] = pq;
        out[b * 100 + 40 + scale] = pm;
        out[b * 100 + 60 + scale] = lac;
        out[b * 100 + 80 + scale] = fd;
    }
}

extern "C" void kernel_launch(void* const* d_in, const int* in_sizes, int n_in,
                              void* d_out, int out_size, void* d_ws, size_t ws_size,
                              hipStream_t stream)
{
    Ptrs ptrs;
    for (int i = 0; i < NSCALES; i++) ptrs.p[i] = (const float*)d_in[i];

    Starts st;
    int acc = 0;
    for (int i = 0; i < NSCALES; i++) {
        st.chunkStart[i] = acc;
        int s = 3 + 2 * i, s2 = s * s;
        acc += (IMGS_PER_SCALE * s2 + CHUNKPX - 1) / CHUNKPX;
    }

    int* bgCnt = (int*)d_ws;                    // [TOTAL_IMGS]
    int* wsCnt = bgCnt + TOTAL_IMGS;
    int* wsN   = wsCnt + TOTAL_IMGS;
    int* wsM   = wsN + TOTAL_IMGS;

    hipMemsetAsync(bgCnt, 0, TOTAL_IMGS * sizeof(int), stream);
    count_kernel<<<acc, THREADS, 0, stream>>>(ptrs, st, bgCnt);
    cc_kernel<<<TOTAL_IMGS / 64, THREADS, 0, stream>>>(ptrs, bgCnt, wsCnt, wsN, wsM);
    final_kernel<<<NSCALES, THREADS, 0, stream>>>(wsCnt, wsN, wsM, (float*)d_out);
}